// Round 1
// baseline (713.857 us; speedup 1.0000x reference)
//
#include <hip/hip_runtime.h>
#include <stdint.h>

typedef unsigned long long u64;

// ---------------------------------------------------------------------------
// Binarized GraphSAGE, 2 layers.
// Core trick: bin_act rows are stored as sign-bits + alpha (20B / 36B per row),
// and every bin_linear reduces to popcount(x_bits ^ w_bits). The rel-linear is
// pushed through scatter_mean (linearity), so neither xb (262MB) nor h (21MB)
// is ever materialized. The only large memory traffic is one pass over x.
//
// Bit layouts (must match between activations and weights!):
//   layer1 (n=128): element e -> word (e&1), bit (e>>1)   [float2 interleave]
//   layer2 (n=256): element e -> word (e>>6), bit (e&63)  [natural]
// ---------------------------------------------------------------------------

// ---- bin_act for x: one wave per row (128 floats, float2/lane) -------------
__global__ __launch_bounds__(256) void binact128_kernel(
    const float* __restrict__ x, int nrows,
    ulonglong2* __restrict__ bits, float* __restrict__ alpha)
{
  const int ROWS = 4;
  int lane = threadIdx.x & 63;
  int wid  = blockIdx.x * (blockDim.x >> 6) + (threadIdx.x >> 6);
  int row0 = wid * ROWS;
  for (int j = 0; j < ROWS; j++) {
    int row = row0 + j;
    if (row >= nrows) return;           // wave-uniform condition
    const float* xr = x + (size_t)row * 128;
    float2 v = ((const float2*)xr)[lane];
    float sum = v.x + v.y;
    #pragma unroll
    for (int off = 32; off > 0; off >>= 1) sum += __shfl_xor(sum, off);
    float mu = sum * (1.0f / 128.0f);
    float d0 = v.x - mu, d1 = v.y - mu;
    float ss = d0 * d0 + d1 * d1;
    float sa = fabsf(d0) + fabsf(d1);
    #pragma unroll
    for (int off = 32; off > 0; off >>= 1) {
      ss += __shfl_xor(ss, off);
      sa += __shfl_xor(sa, off);
    }
    float sd = sqrtf(ss * (1.0f / 127.0f));           // ddof=1
    float a  = (sa * (1.0f / 128.0f)) / (sd + 1e-4f);
    u64 b0 = __ballot(v.x > mu);
    u64 b1 = __ballot(v.y > mu);
    if (lane == 0) { bits[row] = make_ulonglong2(b0, b1); alpha[row] = a; }
  }
}

// ---- weight prep: sign bits + m = mean|w| ----------------------------------
__global__ void prep_w128_kernel(const float* __restrict__ w,
    ulonglong2* __restrict__ wbits, float* __restrict__ m)
{
  int o = blockIdx.x, lane = threadIdx.x;
  float2 v = ((const float2*)(w + (size_t)o * 128))[lane];
  u64 b0 = __ballot(v.x > 0.0f);
  u64 b1 = __ballot(v.y > 0.0f);
  float s = fabsf(v.x) + fabsf(v.y);
  #pragma unroll
  for (int off = 32; off > 0; off >>= 1) s += __shfl_xor(s, off);
  if (lane == 0) { wbits[o] = make_ulonglong2(b0, b1); m[o] = s * (1.0f / 128.0f); }
}

__global__ void prep_w256_kernel(const float* __restrict__ w,
    u64* __restrict__ wbits /*4 words per row*/, float* __restrict__ m)
{
  int o = blockIdx.x, lane = threadIdx.x;
  const float* wr = w + (size_t)o * 256;
  float s = 0.0f;
  u64 b[4];
  #pragma unroll
  for (int wd = 0; wd < 4; wd++) {
    float v = wr[wd * 64 + lane];
    s += fabsf(v);
    b[wd] = __ballot(v > 0.0f);
  }
  #pragma unroll
  for (int off = 32; off > 0; off >>= 1) s += __shfl_xor(s, off);
  if (lane == 0) {
    wbits[o * 4 + 0] = b[0]; wbits[o * 4 + 1] = b[1];
    wbits[o * 4 + 2] = b[2]; wbits[o * 4 + 3] = b[3];
    m[o] = s * (1.0f / 256.0f);
  }
}

// ---- CSR build: histogram, exclusive scan, scatter -------------------------
__global__ void hist_kernel(const int* __restrict__ dst, int E, int* __restrict__ cnt)
{
  int i = blockIdx.x * blockDim.x + threadIdx.x;
  if (i < E) atomicAdd(&cnt[dst[i]], 1);
}

__global__ void exscan_kernel(const int* __restrict__ cnt, int* __restrict__ offs,
                              int* __restrict__ cursor, int n)
{
  __shared__ int tot[256];
  int t = threadIdx.x;
  int chunk = (n + 255) >> 8;
  int b = t * chunk, e = min(b + chunk, n);
  int s = 0;
  for (int i = b; i < e; i++) s += cnt[i];
  tot[t] = s;
  __syncthreads();
  for (int off = 1; off < 256; off <<= 1) {
    int v = (t >= off) ? tot[t - off] : 0;
    __syncthreads();
    tot[t] += v;
    __syncthreads();
  }
  int run = (t == 0) ? 0 : tot[t - 1];
  for (int i = b; i < e; i++) {
    offs[i] = run; cursor[i] = run; run += cnt[i];
  }
  if (t == 255) offs[n] = tot[255];
}

__global__ void scatter_kernel(const int* __restrict__ dst, int E,
                               int* __restrict__ cursor, int* __restrict__ eidx)
{
  int i = blockIdx.x * blockDim.x + threadIdx.x;
  if (i < E) { int p = atomicAdd(&cursor[dst[i]], 1); eidx[p] = i; }
}

// ---- layer 1 fused: scatter-mean + both bin_linears + relu + bin_act(h) ----
// one block per dst node; thread t computes output feature o=t (HID=256)
__global__ __launch_bounds__(256) void layer1_kernel(
    const ulonglong2* __restrict__ bits1, const float* __restrict__ alpha1,
    const int* __restrict__ offs, const int* __restrict__ eidx,
    const int* __restrict__ src,
    const ulonglong2* __restrict__ wb_rel, const float* __restrict__ m_rel,
    const float* __restrict__ b_rel,
    const ulonglong2* __restrict__ wb_root, const float* __restrict__ m_root,
    const float* __restrict__ b_root,
    u64* __restrict__ bits2, float* __restrict__ alpha2)
{
  int d = blockIdx.x, t = threadIdx.x;
  ulonglong2 wr = wb_rel[t];
  int s0 = offs[d], s1 = offs[d + 1];
  float acc = 0.0f;
  for (int i = s0; i < s1; i++) {
    int e = eidx[i];
    int sn = src[e];
    ulonglong2 bv = bits1[sn];
    float a = alpha1[sn];
    int pc = __popcll(bv.x ^ wr.x) + __popcll(bv.y ^ wr.y);
    acc += a * (float)(128 - 2 * pc);
  }
  int cnt = s1 - s0;
  float invc = 1.0f / (float)(cnt > 0 ? cnt : 1);
  ulonglong2 xb = bits1[d];          // xt = bin_act(x[:n1]) row d
  float ax = alpha1[d];
  ulonglong2 wt = wb_root[t];
  int pcr = __popcll(xb.x ^ wt.x) + __popcll(xb.y ^ wt.y);
  float z = m_rel[t] * acc * invc + b_rel[t]
          + m_root[t] * ax * (float)(128 - 2 * pcr) + b_root[t];
  z = fmaxf(z, 0.0f);                // relu

  // fused bin_act over the 256 z values of this row (ddof=255)
  int lane = t & 63, wv = t >> 6;
  __shared__ float redS[4], redSS[4], redSA[4];
  float s = z;
  #pragma unroll
  for (int off = 32; off > 0; off >>= 1) s += __shfl_xor(s, off);
  if (lane == 0) redS[wv] = s;
  __syncthreads();
  float mu = (redS[0] + redS[1] + redS[2] + redS[3]) * (1.0f / 256.0f);
  float dv = z - mu;
  float ss = dv * dv, sa = fabsf(dv);
  #pragma unroll
  for (int off = 32; off > 0; off >>= 1) {
    ss += __shfl_xor(ss, off);
    sa += __shfl_xor(sa, off);
  }
  if (lane == 0) { redSS[wv] = ss; redSA[wv] = sa; }
  __syncthreads();
  float sst = redSS[0] + redSS[1] + redSS[2] + redSS[3];
  float sat = redSA[0] + redSA[1] + redSA[2] + redSA[3];
  float sd = sqrtf(sst * (1.0f / 255.0f));
  float a2 = (sat * (1.0f / 256.0f)) / (sd + 1e-4f);
  u64 bb = __ballot(z > mu);         // word wv = elements wv*64..wv*64+63
  if (lane == 0) bits2[(size_t)d * 4 + wv] = bb;
  if (t == 0) alpha2[d] = a2;
}

// ---- layer 2 fused: scatter-mean + bin_linears + log_softmax ---------------
// one wave per dst node; lane o computes output class o (OUT=64)
__global__ __launch_bounds__(64) void layer2_kernel(
    const u64* __restrict__ bits2, const float* __restrict__ alpha2,
    const int* __restrict__ offs, const int* __restrict__ eidx,
    const int* __restrict__ src,
    const u64* __restrict__ wb_rel, const float* __restrict__ m_rel,
    const float* __restrict__ b_rel,
    const u64* __restrict__ wb_root, const float* __restrict__ m_root,
    const float* __restrict__ b_root,
    float* __restrict__ out)
{
  int d = blockIdx.x, o = threadIdx.x;
  u64 w0 = wb_rel[o * 4 + 0], w1 = wb_rel[o * 4 + 1];
  u64 w2 = wb_rel[o * 4 + 2], w3 = wb_rel[o * 4 + 3];
  int s0 = offs[d], s1 = offs[d + 1];
  float acc = 0.0f;
  for (int i = s0; i < s1; i++) {
    int e = eidx[i];
    int sn = src[e];
    const u64* bp = bits2 + (size_t)sn * 4;
    float a = alpha2[sn];
    int pc = __popcll(bp[0] ^ w0) + __popcll(bp[1] ^ w1)
           + __popcll(bp[2] ^ w2) + __popcll(bp[3] ^ w3);
    acc += a * (float)(256 - 2 * pc);
  }
  int cnt = s1 - s0;
  float invc = 1.0f / (float)(cnt > 0 ? cnt : 1);
  const u64* xp = bits2 + (size_t)d * 4;   // xt2 = bin_act(h[:n2]) row d
  float ax = alpha2[d];
  int pcr = __popcll(xp[0] ^ wb_root[o * 4 + 0]) + __popcll(xp[1] ^ wb_root[o * 4 + 1])
          + __popcll(xp[2] ^ wb_root[o * 4 + 2]) + __popcll(xp[3] ^ wb_root[o * 4 + 3]);
  float z = m_rel[o] * acc * invc + b_rel[o]
          + m_root[o] * ax * (float)(256 - 2 * pcr) + b_root[o];
  // log_softmax over the 64 classes (one wave)
  float mx = z;
  #pragma unroll
  for (int off = 32; off > 0; off >>= 1) mx = fmaxf(mx, __shfl_xor(mx, off));
  float ex = expf(z - mx);
  float se = ex;
  #pragma unroll
  for (int off = 32; off > 0; off >>= 1) se += __shfl_xor(se, off);
  out[(size_t)d * 64 + o] = z - mx - logf(se);
}

// ---------------------------------------------------------------------------
extern "C" void kernel_launch(void* const* d_in, const int* in_sizes, int n_in,
                              void* d_out, int out_size, void* d_ws, size_t ws_size,
                              hipStream_t stream)
{
  const float* x       = (const float*)d_in[0];
  const int*   src1    = (const int*)d_in[1];
  const int*   dst1    = (const int*)d_in[2];
  const int*   src2    = (const int*)d_in[3];
  const int*   dst2    = (const int*)d_in[4];
  const float* w_rel1  = (const float*)d_in[5];
  const float* b_rel1  = (const float*)d_in[6];
  const float* w_root1 = (const float*)d_in[7];
  const float* b_root1 = (const float*)d_in[8];
  const float* w_rel2  = (const float*)d_in[9];
  const float* b_rel2  = (const float*)d_in[10];
  const float* w_root2 = (const float*)d_in[11];
  const float* b_root2 = (const float*)d_in[12];

  const int IN  = 128;
  const int HID = in_sizes[6];            // 256
  const int OUT = in_sizes[10];           // 64
  const int N0  = in_sizes[0] / IN;       // 512000
  const int E1  = in_sizes[1];            // 512000
  const int E2  = in_sizes[3];            // 20480
  const int N1  = 20480;                  // n1 (device scalar; fixed shape for this problem)
  const int N2  = out_size / OUT;         // 2048
  (void)n_in; (void)ws_size;

  // workspace carve-up (~13.5 MB total)
  char* p = (char*)d_ws;
  auto alloc = [&](size_t bytes) {
    char* r = p;
    p += (bytes + 255) & ~(size_t)255;
    return r;
  };
  ulonglong2* bits1 = (ulonglong2*)alloc((size_t)N0 * 16);
  float*      alpha1 = (float*)alloc((size_t)N0 * 4);
  u64*        bits2 = (u64*)alloc((size_t)N1 * 32);
  float*      alpha2 = (float*)alloc((size_t)N1 * 4);
  int*        eidx1 = (int*)alloc((size_t)E1 * 4);
  int*        eidx2 = (int*)alloc((size_t)E2 * 4);
  int*        cnt1  = (int*)alloc((size_t)(N1 + N2) * 4);  // cnt1|cnt2 contiguous
  int*        cnt2  = cnt1 + N1;
  int*        offs1 = (int*)alloc((size_t)(N1 + 1) * 4);
  int*        offs2 = (int*)alloc((size_t)(N2 + 1) * 4);
  int*        cur1  = (int*)alloc((size_t)N1 * 4);
  int*        cur2  = (int*)alloc((size_t)N2 * 4);
  ulonglong2* wbr1  = (ulonglong2*)alloc((size_t)HID * 16);
  ulonglong2* wbt1  = (ulonglong2*)alloc((size_t)HID * 16);
  u64*        wbr2  = (u64*)alloc((size_t)OUT * 32);
  u64*        wbt2  = (u64*)alloc((size_t)OUT * 32);
  float*      m_r1  = (float*)alloc((size_t)HID * 4);
  float*      m_t1  = (float*)alloc((size_t)HID * 4);
  float*      m_r2  = (float*)alloc((size_t)OUT * 4);
  float*      m_t2  = (float*)alloc((size_t)OUT * 4);

  hipMemsetAsync(cnt1, 0, (size_t)(N1 + N2) * 4, stream);

  prep_w128_kernel<<<HID, 64, 0, stream>>>(w_rel1, wbr1, m_r1);
  prep_w128_kernel<<<HID, 64, 0, stream>>>(w_root1, wbt1, m_t1);
  prep_w256_kernel<<<OUT, 64, 0, stream>>>(w_rel2, wbr2, m_r2);
  prep_w256_kernel<<<OUT, 64, 0, stream>>>(w_root2, wbt2, m_t2);

  {
    int waves  = (N0 + 3) / 4;     // 4 rows per wave
    int blocks = (waves + 3) / 4;  // 4 waves per block
    binact128_kernel<<<blocks, 256, 0, stream>>>(x, N0, bits1, alpha1);
  }

  hist_kernel<<<(E1 + 255) / 256, 256, 0, stream>>>(dst1, E1, cnt1);
  exscan_kernel<<<1, 256, 0, stream>>>(cnt1, offs1, cur1, N1);
  scatter_kernel<<<(E1 + 255) / 256, 256, 0, stream>>>(dst1, E1, cur1, eidx1);
  layer1_kernel<<<N1, 256, 0, stream>>>(bits1, alpha1, offs1, eidx1, src1,
                                        wbr1, m_r1, b_rel1, wbt1, m_t1, b_root1,
                                        bits2, alpha2);

  hist_kernel<<<(E2 + 255) / 256, 256, 0, stream>>>(dst2, E2, cnt2);
  exscan_kernel<<<1, 256, 0, stream>>>(cnt2, offs2, cur2, N2);
  scatter_kernel<<<(E2 + 255) / 256, 256, 0, stream>>>(dst2, E2, cur2, eidx2);
  layer2_kernel<<<N2, 64, 0, stream>>>(bits2, alpha2, offs2, eidx2, src2,
                                       wbr2, m_r2, b_rel2, wbt2, m_t2, b_root2,
                                       (float*)d_out);
}

// Round 2
// 531.068 us; speedup vs baseline: 1.3442x; 1.3442x over previous
//
#include <hip/hip_runtime.h>
#include <stdint.h>

typedef unsigned long long u64;

// ---------------------------------------------------------------------------
// Binarized GraphSAGE, 2 layers. bin_act rows = sign bits + alpha; bin_linear =
// popcount(x^w). rel-linear pushed through scatter_mean (linearity). Layer1 is
// wave-per-node with register-staged edges + shfl broadcast (no serial
// dependent-load chain, no LDS, no block barrier).
//
// Bit layouts (activations and weights must match!):
//   layer1 (n=128), float4/lane over 32 lanes: element e=4l+c ->
//       word (c>>1), bit ((c&1)<<5)+l
//   layer2 (n=256): element e -> word (e>>6), bit (e&63)  [natural]
// ---------------------------------------------------------------------------

struct __align__(32) Rec {        // one binarized row: 128 sign bits + alpha
  u64 b0, b1;
  float a;
  float pad0, pad1, pad2;
};

// ---- bin_act(x): 2 rows per wave, float4 per lane, half-wave reductions ----
__global__ __launch_bounds__(256) void binact128_kernel(
    const float* __restrict__ x, int nrows, Rec* __restrict__ rec)
{
  int lane = threadIdx.x & 63;
  int wid  = blockIdx.x * 4 + (threadIdx.x >> 6);
  int h = lane >> 5, l = lane & 31;
  int row = wid * 2 + h;
  int rowc = row < nrows ? row : nrows - 1;
  float4 v = ((const float4*)(x + (size_t)rowc * 128))[l];
  float s = v.x + v.y + v.z + v.w;
  #pragma unroll
  for (int off = 16; off > 0; off >>= 1) s += __shfl_xor(s, off, 64);
  float mu = s * (1.0f / 128.0f);
  float d0 = v.x - mu, d1 = v.y - mu, d2 = v.z - mu, d3 = v.w - mu;
  float ss = d0 * d0 + d1 * d1 + d2 * d2 + d3 * d3;
  float sa = fabsf(d0) + fabsf(d1) + fabsf(d2) + fabsf(d3);
  #pragma unroll
  for (int off = 16; off > 0; off >>= 1) {
    ss += __shfl_xor(ss, off, 64);
    sa += __shfl_xor(sa, off, 64);
  }
  float sd = sqrtf(ss * (1.0f / 127.0f));            // ddof=1
  float a  = (sa * (1.0f / 128.0f)) / (sd + 1e-4f);
  u64 b0 = __ballot(v.x > mu);
  u64 b1 = __ballot(v.y > mu);
  u64 b2 = __ballot(v.z > mu);
  u64 b3 = __ballot(v.w > mu);
  u64 w0, w1;
  if (h == 0) {
    w0 = (b0 & 0xffffffffull) | ((b1 & 0xffffffffull) << 32);
    w1 = (b2 & 0xffffffffull) | ((b3 & 0xffffffffull) << 32);
  } else {
    w0 = (b0 >> 32) | ((b1 >> 32) << 32);
    w1 = (b2 >> 32) | ((b3 >> 32) << 32);
  }
  if (l == 0 && row < nrows) {
    Rec* rp = &rec[row];
    rp->b0 = w0; rp->b1 = w1; rp->a = a;
  }
}

// ---- weight prep (128-in): identical bit layout to binact128 ---------------
__global__ void prep_w128_kernel(const float* __restrict__ w,
    ulonglong2* __restrict__ wbits, float* __restrict__ m)
{
  int lane = threadIdx.x;
  int h = lane >> 5, l = lane & 31;
  int row = blockIdx.x * 2 + h;
  float4 v = ((const float4*)(w + (size_t)row * 128))[l];
  float s = fabsf(v.x) + fabsf(v.y) + fabsf(v.z) + fabsf(v.w);
  #pragma unroll
  for (int off = 16; off > 0; off >>= 1) s += __shfl_xor(s, off, 64);
  u64 b0 = __ballot(v.x > 0.0f);
  u64 b1 = __ballot(v.y > 0.0f);
  u64 b2 = __ballot(v.z > 0.0f);
  u64 b3 = __ballot(v.w > 0.0f);
  u64 w0, w1;
  if (h == 0) {
    w0 = (b0 & 0xffffffffull) | ((b1 & 0xffffffffull) << 32);
    w1 = (b2 & 0xffffffffull) | ((b3 & 0xffffffffull) << 32);
  } else {
    w0 = (b0 >> 32) | ((b1 >> 32) << 32);
    w1 = (b2 >> 32) | ((b3 >> 32) << 32);
  }
  if (l == 0) {
    wbits[row] = make_ulonglong2(w0, w1);
    m[row] = s * (1.0f / 128.0f);
  }
}

__global__ void prep_w256_kernel(const float* __restrict__ w,
    u64* __restrict__ wbits /*4 words per row*/, float* __restrict__ m)
{
  int o = blockIdx.x, lane = threadIdx.x;
  const float* wr = w + (size_t)o * 256;
  float s = 0.0f;
  u64 b[4];
  #pragma unroll
  for (int wd = 0; wd < 4; wd++) {
    float v = wr[wd * 64 + lane];
    s += fabsf(v);
    b[wd] = __ballot(v > 0.0f);
  }
  #pragma unroll
  for (int off = 32; off > 0; off >>= 1) s += __shfl_xor(s, off);
  if (lane == 0) {
    wbits[o * 4 + 0] = b[0]; wbits[o * 4 + 1] = b[1];
    wbits[o * 4 + 2] = b[2]; wbits[o * 4 + 3] = b[3];
    m[o] = s * (1.0f / 256.0f);
  }
}

// ---- CSR build: histogram, exclusive scan, scatter (reordered src) ---------
__global__ void hist_kernel(const int* __restrict__ dst, int E, int* __restrict__ cnt)
{
  int i = blockIdx.x * blockDim.x + threadIdx.x;
  if (i < E) atomicAdd(&cnt[dst[i]], 1);
}

__global__ __launch_bounds__(1024) void exscan_kernel(
    const int* __restrict__ cnt, int* __restrict__ offs,
    int* __restrict__ cursor, int n)
{
  __shared__ int tot[1024];
  int t = threadIdx.x;
  int chunk = (n + 1023) >> 10;
  int b = t * chunk, e = min(b + chunk, n);
  int s = 0;
  for (int i = b; i < e; i++) s += cnt[i];
  tot[t] = s;
  __syncthreads();
  for (int off = 1; off < 1024; off <<= 1) {
    int v = (t >= off) ? tot[t - off] : 0;
    __syncthreads();
    tot[t] += v;
    __syncthreads();
  }
  int run = (t == 0) ? 0 : tot[t - 1];
  for (int i = b; i < e; i++) {
    offs[i] = run; cursor[i] = run; run += cnt[i];
  }
  if (t == 1023) offs[n] = tot[1023];
}

__global__ void scatter_kernel(const int* __restrict__ dst, const int* __restrict__ src,
                               int E, int* __restrict__ cursor, int* __restrict__ srcs)
{
  int i = blockIdx.x * blockDim.x + threadIdx.x;
  if (i < E) { int p = atomicAdd(&cursor[dst[i]], 1); srcs[p] = src[i]; }
}

// ---- layer 1 fused: scatter-mean + both bin_linears + relu + bin_act(h) ----
// one WAVE per dst node (4 waves/block); lane owns features f = j*64+lane
__global__ __launch_bounds__(256) void layer1_kernel(
    const Rec* __restrict__ rec1,
    const int* __restrict__ offs, const int* __restrict__ srcs,
    const ulonglong2* __restrict__ wb_rel, const float* __restrict__ m_rel,
    const float* __restrict__ b_rel,
    const ulonglong2* __restrict__ wb_root, const float* __restrict__ m_root,
    const float* __restrict__ b_root,
    u64* __restrict__ bits2, float* __restrict__ alpha2)
{
  int lane = threadIdx.x & 63;
  int d = blockIdx.x * 4 + (threadIdx.x >> 6);

  ulonglong2 wr[4], wt[4];
  float mr[4], br[4], mt[4], bt[4];
  #pragma unroll
  for (int j = 0; j < 4; j++) {
    int f = j * 64 + lane;
    wr[j] = wb_rel[f];  mr[j] = m_rel[f];  br[j] = b_rel[f];
    wt[j] = wb_root[f]; mt[j] = m_root[f]; bt[j] = b_root[f];
  }

  int s0 = offs[d], s1 = offs[d + 1];
  float acc2[4] = {0.f, 0.f, 0.f, 0.f};   // sum over edges of a * popc
  float suma = 0.f;                       // sum over edges of a

  for (int base = s0; base < s1; base += 64) {
    int nn = min(64, s1 - base);
    u64 rb0 = 0, rb1 = 0; float ra = 0.f;
    if (lane < nn) {
      int sn = srcs[base + lane];
      const Rec* rp = &rec1[sn];
      rb0 = rp->b0; rb1 = rp->b1; ra = rp->a;
    }
    for (int i = 0; i < nn; i++) {
      u64 bx = __shfl(rb0, i, 64);
      u64 by = __shfl(rb1, i, 64);
      float a = __shfl(ra, i, 64);
      suma += a;
      #pragma unroll
      for (int j = 0; j < 4; j++) {
        int pc = __popcll(bx ^ wr[j].x) + __popcll(by ^ wr[j].y);
        acc2[j] += a * (float)pc;
      }
    }
  }

  float invc = (s1 > s0) ? 1.0f / (float)(s1 - s0) : 1.0f;
  const Rec* rd = &rec1[d];               // xt = bin_act(x[:n1]) row d
  u64 xb0 = rd->b0, xb1 = rd->b1;
  float ax = rd->a;

  float z[4];
  #pragma unroll
  for (int j = 0; j < 4; j++) {
    int pcr = __popcll(xb0 ^ wt[j].x) + __popcll(xb1 ^ wt[j].y);
    float rel = mr[j] * (128.0f * suma - 2.0f * acc2[j]) * invc + br[j];
    float rot = mt[j] * ax * (float)(128 - 2 * pcr) + bt[j];
    z[j] = fmaxf(rel + rot, 0.0f);        // relu
  }

  // fused bin_act over this node's 256 z values (all wave-local)
  float s = z[0] + z[1] + z[2] + z[3];
  #pragma unroll
  for (int off = 32; off > 0; off >>= 1) s += __shfl_xor(s, off);
  float mu = s * (1.0f / 256.0f);
  float ss = 0.f, sa = 0.f;
  #pragma unroll
  for (int j = 0; j < 4; j++) {
    float dv = z[j] - mu;
    ss += dv * dv; sa += fabsf(dv);
  }
  #pragma unroll
  for (int off = 32; off > 0; off >>= 1) {
    ss += __shfl_xor(ss, off);
    sa += __shfl_xor(sa, off);
  }
  float sd = sqrtf(ss * (1.0f / 255.0f));  // ddof=1
  float a2 = (sa * (1.0f / 256.0f)) / (sd + 1e-4f);
  u64 wd0 = __ballot(z[0] > mu);           // word j bit l = feature j*64+l
  u64 wd1 = __ballot(z[1] > mu);
  u64 wd2 = __ballot(z[2] > mu);
  u64 wd3 = __ballot(z[3] > mu);
  if (lane == 0) {
    ulonglong2* bp = (ulonglong2*)(bits2 + (size_t)d * 4);
    bp[0] = make_ulonglong2(wd0, wd1);
    bp[1] = make_ulonglong2(wd2, wd3);
    alpha2[d] = a2;
  }
}

// ---- layer 2 fused: scatter-mean + bin_linears + log_softmax ---------------
// one wave per dst node; lane o computes output class o (OUT=64)
__global__ __launch_bounds__(64) void layer2_kernel(
    const u64* __restrict__ bits2, const float* __restrict__ alpha2,
    const int* __restrict__ offs, const int* __restrict__ srcs,
    const u64* __restrict__ wb_rel, const float* __restrict__ m_rel,
    const float* __restrict__ b_rel,
    const u64* __restrict__ wb_root, const float* __restrict__ m_root,
    const float* __restrict__ b_root,
    float* __restrict__ out)
{
  int d = blockIdx.x, o = threadIdx.x;
  u64 w0 = wb_rel[o * 4 + 0], w1 = wb_rel[o * 4 + 1];
  u64 w2 = wb_rel[o * 4 + 2], w3 = wb_rel[o * 4 + 3];
  int s0 = offs[d], s1 = offs[d + 1];
  float acc = 0.0f;
  for (int base = s0; base < s1; base += 64) {
    int nn = min(64, s1 - base);
    u64 rb0 = 0, rb1 = 0, rb2 = 0, rb3 = 0; float ra = 0.f;
    if (o < nn) {
      int sn = srcs[base + o];
      const u64* bp = bits2 + (size_t)sn * 4;
      rb0 = bp[0]; rb1 = bp[1]; rb2 = bp[2]; rb3 = bp[3];
      ra = alpha2[sn];
    }
    for (int i = 0; i < nn; i++) {
      u64 bx0 = __shfl(rb0, i, 64);
      u64 bx1 = __shfl(rb1, i, 64);
      u64 bx2 = __shfl(rb2, i, 64);
      u64 bx3 = __shfl(rb3, i, 64);
      float a = __shfl(ra, i, 64);
      int pc = __popcll(bx0 ^ w0) + __popcll(bx1 ^ w1)
             + __popcll(bx2 ^ w2) + __popcll(bx3 ^ w3);
      acc += a * (float)(256 - 2 * pc);
    }
  }
  int cnt = s1 - s0;
  float invc = 1.0f / (float)(cnt > 0 ? cnt : 1);
  const u64* xp = bits2 + (size_t)d * 4;   // xt2 = bin_act(h[:n2]) row d
  float ax = alpha2[d];
  int pcr = __popcll(xp[0] ^ wb_root[o * 4 + 0]) + __popcll(xp[1] ^ wb_root[o * 4 + 1])
          + __popcll(xp[2] ^ wb_root[o * 4 + 2]) + __popcll(xp[3] ^ wb_root[o * 4 + 3]);
  float z = m_rel[o] * acc * invc + b_rel[o]
          + m_root[o] * ax * (float)(256 - 2 * pcr) + b_root[o];
  // log_softmax over the 64 classes (one wave)
  float mx = z;
  #pragma unroll
  for (int off = 32; off > 0; off >>= 1) mx = fmaxf(mx, __shfl_xor(mx, off));
  float ex = expf(z - mx);
  float se = ex;
  #pragma unroll
  for (int off = 32; off > 0; off >>= 1) se += __shfl_xor(se, off);
  out[(size_t)d * 64 + o] = z - mx - logf(se);
}

// ---------------------------------------------------------------------------
extern "C" void kernel_launch(void* const* d_in, const int* in_sizes, int n_in,
                              void* d_out, int out_size, void* d_ws, size_t ws_size,
                              hipStream_t stream)
{
  const float* x       = (const float*)d_in[0];
  const int*   src1    = (const int*)d_in[1];
  const int*   dst1    = (const int*)d_in[2];
  const int*   src2    = (const int*)d_in[3];
  const int*   dst2    = (const int*)d_in[4];
  const float* w_rel1  = (const float*)d_in[5];
  const float* b_rel1  = (const float*)d_in[6];
  const float* w_root1 = (const float*)d_in[7];
  const float* b_root1 = (const float*)d_in[8];
  const float* w_rel2  = (const float*)d_in[9];
  const float* b_rel2  = (const float*)d_in[10];
  const float* w_root2 = (const float*)d_in[11];
  const float* b_root2 = (const float*)d_in[12];

  const int IN  = 128;
  const int HID = in_sizes[6];            // 256
  const int OUT = in_sizes[10];           // 64
  const int N0  = in_sizes[0] / IN;       // 512000
  const int E1  = in_sizes[1];            // 512000
  const int E2  = in_sizes[3];            // 20480
  const int N1  = 20480;                  // n1 (fixed shape for this problem)
  const int N2  = out_size / OUT;         // 2048
  (void)n_in; (void)ws_size;

  char* p = (char*)d_ws;
  auto alloc = [&](size_t bytes) {
    char* r = p;
    p += (bytes + 255) & ~(size_t)255;
    return r;
  };
  Rec*   rec1   = (Rec*)alloc((size_t)N0 * sizeof(Rec));   // 16.4 MB
  u64*   bits2  = (u64*)alloc((size_t)N1 * 32);
  float* alpha2 = (float*)alloc((size_t)N1 * 4);
  int*   srcs1  = (int*)alloc((size_t)E1 * 4);
  int*   srcs2  = (int*)alloc((size_t)E2 * 4);
  int*   cnt1   = (int*)alloc((size_t)(N1 + N2) * 4);
  int*   cnt2   = cnt1 + N1;
  int*   offs1  = (int*)alloc((size_t)(N1 + 1) * 4);
  int*   offs2  = (int*)alloc((size_t)(N2 + 1) * 4);
  int*   cur1   = (int*)alloc((size_t)N1 * 4);
  int*   cur2   = (int*)alloc((size_t)N2 * 4);
  ulonglong2* wbr1 = (ulonglong2*)alloc((size_t)HID * 16);
  ulonglong2* wbt1 = (ulonglong2*)alloc((size_t)HID * 16);
  u64*   wbr2   = (u64*)alloc((size_t)OUT * 32);
  u64*   wbt2   = (u64*)alloc((size_t)OUT * 32);
  float* m_r1   = (float*)alloc((size_t)HID * 4);
  float* m_t1   = (float*)alloc((size_t)HID * 4);
  float* m_r2   = (float*)alloc((size_t)OUT * 4);
  float* m_t2   = (float*)alloc((size_t)OUT * 4);

  hipMemsetAsync(cnt1, 0, (size_t)(N1 + N2) * 4, stream);

  prep_w128_kernel<<<HID / 2, 64, 0, stream>>>(w_rel1, wbr1, m_r1);
  prep_w128_kernel<<<HID / 2, 64, 0, stream>>>(w_root1, wbt1, m_t1);
  prep_w256_kernel<<<OUT, 64, 0, stream>>>(w_rel2, wbr2, m_r2);
  prep_w256_kernel<<<OUT, 64, 0, stream>>>(w_root2, wbt2, m_t2);

  {
    int waves  = (N0 + 1) / 2;     // 2 rows per wave
    int blocks = (waves + 3) / 4;  // 4 waves per block
    binact128_kernel<<<blocks, 256, 0, stream>>>(x, N0, rec1);
  }

  hist_kernel<<<(E1 + 255) / 256, 256, 0, stream>>>(dst1, E1, cnt1);
  exscan_kernel<<<1, 1024, 0, stream>>>(cnt1, offs1, cur1, N1);
  scatter_kernel<<<(E1 + 255) / 256, 256, 0, stream>>>(dst1, src1, E1, cur1, srcs1);
  layer1_kernel<<<N1 / 4, 256, 0, stream>>>(rec1, offs1, srcs1,
                                            wbr1, m_r1, b_rel1, wbt1, m_t1, b_root1,
                                            bits2, alpha2);

  hist_kernel<<<(E2 + 255) / 256, 256, 0, stream>>>(dst2, E2, cnt2);
  exscan_kernel<<<1, 1024, 0, stream>>>(cnt2, offs2, cur2, N2);
  scatter_kernel<<<(E2 + 255) / 256, 256, 0, stream>>>(dst2, src2, E2, cur2, srcs2);
  layer2_kernel<<<N2, 64, 0, stream>>>(bits2, alpha2, offs2, srcs2,
                                       wbr2, m_r2, b_rel2, wbt2, m_t2, b_root2,
                                       (float*)d_out);
}